// Round 7
// baseline (448.026 us; speedup 1.0000x reference)
//
#include <hip/hip_runtime.h>

#define EPSN 1e-12f
#define SCALE_F 0.044194173824159216f  // 512^-0.5

typedef __bf16 bf16x8 __attribute__((ext_vector_type(8)));
typedef __bf16 bf16x4 __attribute__((ext_vector_type(4)));
typedef float  f32x4  __attribute__((ext_vector_type(4)));

__device__ __forceinline__ void gld16(const void* src, void* dst) {
  __builtin_amdgcn_global_load_lds(
      (const __attribute__((address_space(1))) unsigned int*)src,
      (__attribute__((address_space(3))) unsigned int*)dst, 16, 0, 0);
}

// ---------------- prep: WqT/WkT bf16 [d][c] = W[c][d], LDS tile transpose ----------------
__global__ __launch_bounds__(256) void k_prep_t(const float* __restrict__ Wq,
                                                const float* __restrict__ Wk,
                                                __bf16* __restrict__ WqT,
                                                __bf16* __restrict__ WkT) {
  __shared__ float Tq[32][33], Tk[32][33];
  const int c0 = blockIdx.x * 32, d0 = blockIdx.y * 32;
  const int dx = threadIdx.x, cy = threadIdx.y;  // 32, 8
  #pragma unroll
  for (int p = 0; p < 4; ++p) {
    int c = cy + p * 8;
    Tq[c][dx] = Wq[(size_t)(c0 + c) * 512 + d0 + dx];
    Tk[c][dx] = Wk[(size_t)(c0 + c) * 512 + d0 + dx];
  }
  __syncthreads();
  #pragma unroll
  for (int p = 0; p < 4; ++p) {
    int d = cy + p * 8;
    WqT[(size_t)(d0 + d) * 512 + c0 + dx] = (__bf16)Tq[dx][d];
    WkT[(size_t)(d0 + d) * 512 + c0 + dx] = (__bf16)Tk[dx][d];
  }
}

// ---- prep: WcT[d][kk]: kk<512 -> (Wp@Wf)[kk][d]; kk>=512 -> Wf[kk-512][d]. bpf[d]=bp@Wf+bf
__global__ __launch_bounds__(512) void k_prep_w(const float* __restrict__ Wp,
                                                const float* __restrict__ Wf,
                                                const float* __restrict__ bp,
                                                const float* __restrict__ bfv,
                                                __bf16* __restrict__ WcT,
                                                float* __restrict__ bpf) {
  int kk = blockIdx.x;   // 512
  int d  = threadIdx.x;  // 512
  float a0 = 0.f, a1 = 0.f, a2 = 0.f, a3 = 0.f;
  for (int c = 0; c < 512; c += 4) {
    a0 = fmaf(Wp[kk * 512 + c],     Wf[(size_t)c * 512 + d],         a0);
    a1 = fmaf(Wp[kk * 512 + c + 1], Wf[(size_t)(c + 1) * 512 + d],   a1);
    a2 = fmaf(Wp[kk * 512 + c + 2], Wf[(size_t)(c + 2) * 512 + d],   a2);
    a3 = fmaf(Wp[kk * 512 + c + 3], Wf[(size_t)(c + 3) * 512 + d],   a3);
  }
  WcT[(size_t)d * 1024 + kk]       = (__bf16)((a0 + a1) + (a2 + a3));
  WcT[(size_t)d * 1024 + 512 + kk] = (__bf16)Wf[(size_t)kk * 512 + d];
  if (kk == 0) {
    float b0 = 0.f, b1 = 0.f;
    for (int c = 0; c < 512; c += 2) {
      b0 = fmaf(bp[c],     Wf[(size_t)c * 512 + d],       b0);
      b1 = fmaf(bp[c + 1], Wf[(size_t)(c + 1) * 512 + d], b1);
    }
    bpf[d] = b0 + b1 + bfv[d];
  }
}

// ---------------- Q or K GEMM + bias + row l2norm (+g, pctx for Q) ----------------
// Ring-3 LDS, prefetch-distance-2, 1 barrier/step. Tile 64 tok x 512 d, 8 waves.
__global__ __launch_bounds__(512) void k_qk(const float* __restrict__ x,
                                            const __bf16* __restrict__ WqT,
                                            const __bf16* __restrict__ WkT,
                                            const float* __restrict__ bq,
                                            const float* __restrict__ bk,
                                            const float* __restrict__ wg,
                                            __bf16* __restrict__ Qn,
                                            __bf16* __restrict__ Kn,
                                            float* __restrict__ pctx,
                                            float* __restrict__ pgsq) {
  __shared__ __align__(1024) unsigned char stg[3][36864];   // per buf: As 4KB | Bs 32KB
  __shared__ float red[8][64], redG[8][64], invv[64], gs[64];
  const int t = threadIdx.x, lane = t & 63, w = t >> 6;
  const int li = lane & 15, lq = lane >> 4;
  const int isK = blockIdx.x & 1, nx = blockIdx.x >> 1;
  const int n0 = nx * 64, b = blockIdx.y;
  const __bf16* Wt  = isK ? WkT : WqT;
  const float* bias = isK ? bk : bq;
  __bf16* dst       = isK ? Kn : Qn;

  // A staging: wave w -> region ra = w&3 (rows ra*16+li), half h = w>>2 (k sub-quad)
  const int ra = w & 3, h = w >> 2;
  int nc = n0 + ra * 16 + li; if (nc > 783) nc = 783;
  const float* xbase = x + ((size_t)b * 512 + lq * 8 + h * 4) * 784 + nc;
  // B staging: fragment-ordered gather (region r rows r*16+li, k-chunk lq)
  const __bf16* wsrc = Wt + (size_t)li * 512 + lq * 8;

  float xA[4], xB[4];
  f32x4 acc[4][4] = {};

  auto loadX = [&](float (&xr)[4], int ks) {
    int kk = ks > 15 ? 15 : ks;
    #pragma unroll
    for (int j = 0; j < 4; ++j)
      xr[j] = xbase[(size_t)(kk * 32 + j) * 784];
  };
  auto stageB = [&](int buf, int ks) {
    int kk = ks > 15 ? 15 : ks;
    #pragma unroll
    for (int i = 0; i < 4; ++i) {
      int r = w * 4 + i;
      gld16(wsrc + (size_t)r * 16 * 512 + kk * 32, stg[buf] + 4096 + r * 1024);
    }
  };
  auto writeA = [&](int buf, const float (&xr)[4]) {
    bf16x4 v;
    #pragma unroll
    for (int j = 0; j < 4; ++j) v[j] = (__bf16)xr[j];
    *(bf16x4*)(stg[buf] + ra * 1024 + lane * 16 + h * 8) = v;
  };
  auto mstep = [&](int buf) {
    bf16x8 af[4];
    #pragma unroll
    for (int rb = 0; rb < 4; ++rb)
      af[rb] = *(const bf16x8*)(stg[buf] + rb * 1024 + lane * 16);
    #pragma unroll
    for (int cb = 0; cb < 4; ++cb) {
      bf16x8 bf = *(const bf16x8*)(stg[buf] + 4096 + (w * 4 + cb) * 1024 + lane * 16);
      #pragma unroll
      for (int rb = 0; rb < 4; ++rb)
        acc[rb][cb] = __builtin_amdgcn_mfma_f32_16x16x32_bf16(af[rb], bf, acc[rb][cb], 0, 0, 0);
    }
  };

  // prologue: batches [x0 x1 B0 B1] -> retire x0 -> A0 -> [x2] -> retire x1,B0 -> A1
  loadX(xA, 0); loadX(xB, 1);
  stageB(0, 0); stageB(1, 1);
  asm volatile("s_waitcnt vmcnt(12)" ::: "memory");
  __builtin_amdgcn_sched_barrier(0);
  writeA(0, xA);
  loadX(xA, 2);
  asm volatile("s_waitcnt vmcnt(8) lgkmcnt(0)" ::: "memory");
  __builtin_amdgcn_sched_barrier(0);
  writeA(1, xB);
  __builtin_amdgcn_sched_barrier(0);
  __builtin_amdgcn_s_barrier();

  // step s: issue {x(s+3), B(s+2)}; compute buf s; retire batch s-1; write A(s+2).
#define QK_STEP(S, XNEW, XWR) \
  loadX(XNEW, (S) + 3); \
  stageB(((S) + 2) % 3, (S) + 2); \
  mstep((S) % 3); \
  asm volatile("s_waitcnt vmcnt(8) lgkmcnt(0)" ::: "memory"); \
  __builtin_amdgcn_sched_barrier(0); \
  writeA(((S) + 2) % 3, XWR); \
  __builtin_amdgcn_sched_barrier(0); \
  __builtin_amdgcn_s_barrier();

  QK_STEP(0,  xB, xA)  QK_STEP(1,  xA, xB)  QK_STEP(2,  xB, xA)  QK_STEP(3,  xA, xB)
  QK_STEP(4,  xB, xA)  QK_STEP(5,  xA, xB)  QK_STEP(6,  xB, xA)  QK_STEP(7,  xA, xB)
  QK_STEP(8,  xB, xA)  QK_STEP(9,  xA, xB)  QK_STEP(10, xB, xA)  QK_STEP(11, xA, xB)
  QK_STEP(12, xB, xA)  QK_STEP(13, xA, xB)  QK_STEP(14, xB, xA)  QK_STEP(15, xA, xB)
#undef QK_STEP
  asm volatile("s_waitcnt vmcnt(0)" ::: "memory");   // drain dummies before LDS reuse/exit

  // ---- epilogue: bias, row sumsq (+ g-dot for Q), normalize, store, pctx partial ----
  float bv[4], wv[4];
  #pragma unroll
  for (int cb = 0; cb < 4; ++cb) {
    int col = w * 64 + cb * 16 + li;
    bv[cb] = bias[col];
    wv[cb] = isK ? 0.f : wg[col];
  }
  #pragma unroll
  for (int rb = 0; rb < 4; ++rb)
    #pragma unroll
    for (int cb = 0; cb < 4; ++cb)
      #pragma unroll
      for (int j = 0; j < 4; ++j)
        acc[rb][cb][j] += bv[cb];
  #pragma unroll
  for (int rb = 0; rb < 4; ++rb)
    #pragma unroll
    for (int j = 0; j < 4; ++j) {
      float ss = 0.f, sg = 0.f;
      #pragma unroll
      for (int cb = 0; cb < 4; ++cb) {
        float v = acc[rb][cb][j];
        ss = fmaf(v, v, ss); sg = fmaf(v, wv[cb], sg);
      }
      ss += __shfl_xor(ss, 1); ss += __shfl_xor(ss, 2); ss += __shfl_xor(ss, 4); ss += __shfl_xor(ss, 8);
      sg += __shfl_xor(sg, 1); sg += __shfl_xor(sg, 2); sg += __shfl_xor(sg, 4); sg += __shfl_xor(sg, 8);
      if (li == 0) {
        int row = rb * 16 + lq * 4 + j;
        red[w][row] = ss; redG[w][row] = sg;
      }
    }
  __syncthreads();
  if (t < 64) {
    float ss = 0.f, sg = 0.f;
    #pragma unroll
    for (int wv2 = 0; wv2 < 8; ++wv2) { ss += red[wv2][t]; sg += redG[wv2][t]; }
    float iv = 1.f / fmaxf(sqrtf(ss), EPSN);
    invv[t] = iv;
    if (!isK) {
      float gv = (n0 + t < 784) ? sg * iv : 0.f;
      gs[t] = gv;
      float pg = gv * gv;
      pg += __shfl_xor(pg, 1);  pg += __shfl_xor(pg, 2);  pg += __shfl_xor(pg, 4);
      pg += __shfl_xor(pg, 8);  pg += __shfl_xor(pg, 16); pg += __shfl_xor(pg, 32);
      if (t == 0) pgsq[b * 13 + nx] = pg;
    }
  }
  __syncthreads();
  float pc[4] = {0.f, 0.f, 0.f, 0.f};
  #pragma unroll
  for (int rb = 0; rb < 4; ++rb)
    #pragma unroll
    for (int j = 0; j < 4; ++j) {
      int row = rb * 16 + lq * 4 + j;
      if (n0 + row < 784) {
        float iv = invv[row];
        float gr = isK ? 0.f : gs[row];
        size_t base = ((size_t)b * 784 + n0 + row) * 512 + w * 64 + li;
        #pragma unroll
        for (int cb = 0; cb < 4; ++cb) {
          float qv = acc[rb][cb][j] * iv;
          dst[base + cb * 16] = (__bf16)qv;
          pc[cb] = fmaf(gr, qv, pc[cb]);
        }
      }
    }
  if (!isK) {
    #pragma unroll
    for (int cb = 0; cb < 4; ++cb) {
      pc[cb] += __shfl_xor(pc[cb], 16);
      pc[cb] += __shfl_xor(pc[cb], 32);
    }
    if (lq == 0) {
      #pragma unroll
      for (int cb = 0; cb < 4; ++cb)
        pctx[((size_t)b * 13 + nx) * 512 + w * 64 + cb * 16 + li] = pc[cb];
    }
  }
}

// ---------------- combine: ctx[b,d] = alpha(b) * sum_tiles pctx ----------------
__global__ __launch_bounds__(512) void k_ctx2(const float* __restrict__ pctx,
                                              const float* __restrict__ pgsq,
                                              float* __restrict__ ctx) {
  const int b = blockIdx.x, t = threadIdx.x;
  float tot = 0.f;
  #pragma unroll
  for (int i = 0; i < 13; ++i) tot += pgsq[b * 13 + i];
  float alpha = SCALE_F / fmaxf(sqrtf(tot) * SCALE_F, EPSN);
  float s = 0.f;
  #pragma unroll
  for (int i = 0; i < 13; ++i) s += pctx[((size_t)b * 13 + i) * 512 + t];
  ctx[(size_t)b * 512 + t] = alpha * s;
}

// ---------------- final GEMM: out[b,d,n] = ([ctx.Kn | Qn] @ [Wpf;Wf] + bpf)^T ----------------
// Ring-3, prefetch-2. Tile 64 tok x 256 d, 4 waves, 2 blocks/CU. ctx folded into
// reg-staged A (scale table ctx_lds[0..511]=ctx, [512..1023]=1). B via gld16.
__global__ __launch_bounds__(256, 2) void k_out(const __bf16* __restrict__ Qn,
                                                const __bf16* __restrict__ Kn,
                                                const float* __restrict__ ctx,
                                                const __bf16* __restrict__ WcT,
                                                const float* __restrict__ bpf,
                                                float* __restrict__ out) {
  __shared__ __align__(1024) unsigned char stg[3][20480];   // per buf: As 4KB | Bs 16KB
  __shared__ float ctx_lds[1024];
  const int t = threadIdx.x, lane = t & 63, w = t >> 6;
  const int li = lane & 15, lq = lane >> 4;
  const int n0 = blockIdx.x * 64, d0 = blockIdx.y * 256, b = blockIdx.z;

  // fill ctx table
  #pragma unroll
  for (int i = 0; i < 4; ++i) {
    int idx = t + i * 256;
    ctx_lds[idx] = (idx < 512) ? ctx[(size_t)b * 512 + idx] : 1.0f;
  }
  __syncthreads();

  // A staging: thread t -> region rg = t>>6, chunk ch = t&63 (row rg*16+(ch&15), k (ch>>4)*8)
  const int rg = t >> 6, ch = t & 63;
  const int kq8 = (ch >> 4) * 8;
  int rowg = n0 + rg * 16 + (ch & 15); if (rowg > 783) rowg = 783;
  const size_t rowbase = ((size_t)b * 784 + rowg) * 512;
  // B staging: wave w regions w*4+i, rows (r)*16+li of WcT within d0
  const __bf16* wsrc = WcT + (size_t)(d0 + li) * 1024 + lq * 8;

  bf16x8 aA, aB;
  f32x4 acc[4][4] = {};

  auto loadA = [&](bf16x8& ar, int ks) {
    int kk = ks > 31 ? 31 : ks;
    int kl = kk * 32 + kq8;                 // 0..1023
    const __bf16* src = (kl < 512) ? (Kn + rowbase + kl) : (Qn + rowbase + kl - 512);
    ar = *(const bf16x8*)src;
  };
  auto stageB = [&](int buf, int ks) {
    int kk = ks > 31 ? 31 : ks;
    #pragma unroll
    for (int i = 0; i < 4; ++i) {
      int r = w * 4 + i;
      gld16(wsrc + (size_t)r * 16 * 1024 + kk * 32, stg[buf] + 4096 + r * 1024);
    }
  };
  auto writeA = [&](int buf, bf16x8 ar, int ks) {
    int kk = ks > 31 ? 31 : ks;
    int kl = kk * 32 + kq8;
    f32x4 c0 = *(const f32x4*)&ctx_lds[kl];
    f32x4 c1 = *(const f32x4*)&ctx_lds[kl + 4];
    bf16x8 r;
    #pragma unroll
    for (int j = 0; j < 4; ++j) {
      r[j]     = (__bf16)((float)ar[j]     * c0[j]);
      r[4 + j] = (__bf16)((float)ar[4 + j] * c1[j]);
    }
    *(bf16x8*)(stg[buf] + rg * 1024 + ch * 16) = r;
  };
  auto mstep = [&](int buf) {
    bf16x8 af[4];
    #pragma unroll
    for (int rb = 0; rb < 4; ++rb)
      af[rb] = *(const bf16x8*)(stg[buf] + rb * 1024 + lane * 16);
    #pragma unroll
    for (int cb = 0; cb < 4; ++cb) {
      bf16x8 bf = *(const bf16x8*)(stg[buf] + 4096 + (w * 4 + cb) * 1024 + lane * 16);
      #pragma unroll
      for (int rb = 0; rb < 4; ++rb)
        acc[rb][cb] = __builtin_amdgcn_mfma_f32_16x16x32_bf16(af[rb], bf, acc[rb][cb], 0, 0, 0);
    }
  };

  // prologue: [a0 a1 B0 B1](10) -> retire a0 -> A0 -> [a2] -> retire a1,B0 -> A1
  loadA(aA, 0); loadA(aB, 1);
  stageB(0, 0); stageB(1, 1);
  asm volatile("s_waitcnt vmcnt(9)" ::: "memory");
  __builtin_amdgcn_sched_barrier(0);
  writeA(0, aA, 0);
  loadA(aA, 2);
  asm volatile("s_waitcnt vmcnt(5) lgkmcnt(0)" ::: "memory");
  __builtin_amdgcn_sched_barrier(0);
  writeA(1, aB, 1);
  __builtin_amdgcn_sched_barrier(0);
  __builtin_amdgcn_s_barrier();

#define OUT_STEP(S, ANEW, AWR) \
  loadA(ANEW, (S) + 3); \
  stageB(((S) + 2) % 3, (S) + 2); \
  mstep((S) % 3); \
  asm volatile("s_waitcnt vmcnt(5) lgkmcnt(0)" ::: "memory"); \
  __builtin_amdgcn_sched_barrier(0); \
  writeA(((S) + 2) % 3, AWR, (S) + 2); \
  __builtin_amdgcn_sched_barrier(0); \
  __builtin_amdgcn_s_barrier();

  OUT_STEP(0,  aB, aA)  OUT_STEP(1,  aA, aB)  OUT_STEP(2,  aB, aA)  OUT_STEP(3,  aA, aB)
  OUT_STEP(4,  aB, aA)  OUT_STEP(5,  aA, aB)  OUT_STEP(6,  aB, aA)  OUT_STEP(7,  aA, aB)
  OUT_STEP(8,  aB, aA)  OUT_STEP(9,  aA, aB)  OUT_STEP(10, aB, aA)  OUT_STEP(11, aA, aB)
  OUT_STEP(12, aB, aA)  OUT_STEP(13, aA, aB)  OUT_STEP(14, aB, aA)  OUT_STEP(15, aA, aB)
  OUT_STEP(16, aB, aA)  OUT_STEP(17, aA, aB)  OUT_STEP(18, aB, aA)  OUT_STEP(19, aA, aB)
  OUT_STEP(20, aB, aA)  OUT_STEP(21, aA, aB)  OUT_STEP(22, aB, aA)  OUT_STEP(23, aA, aB)
  OUT_STEP(24, aB, aA)  OUT_STEP(25, aA, aB)  OUT_STEP(26, aB, aA)  OUT_STEP(27, aA, aB)
  OUT_STEP(28, aB, aA)  OUT_STEP(29, aA, aB)  OUT_STEP(30, aB, aA)  OUT_STEP(31, aA, aB)
#undef OUT_STEP
  asm volatile("s_waitcnt vmcnt(0)" ::: "memory");

  // epilogue: + bias, direct coalesced f32x4 stores into out[b,d,n]
  float bv[4];
  #pragma unroll
  for (int cb = 0; cb < 4; ++cb) bv[cb] = bpf[d0 + w * 64 + cb * 16 + li];
  #pragma unroll
  for (int rb = 0; rb < 4; ++rb) {
    int nrow = n0 + rb * 16 + lq * 4;
    if (nrow < 784) {
      #pragma unroll
      for (int cb = 0; cb < 4; ++cb) {
        f32x4 v;
        #pragma unroll
        for (int j = 0; j < 4; ++j) v[j] = acc[rb][cb][j] + bv[cb];
        *(f32x4*)&out[((size_t)b * 512 + d0 + w * 64 + cb * 16 + li) * 784 + nrow] = v;
      }
    }
  }
}

extern "C" void kernel_launch(void* const* d_in, const int* in_sizes, int n_in,
                              void* d_out, int out_size, void* d_ws, size_t ws_size,
                              hipStream_t stream) {
  const float* x   = (const float*)d_in[0];
  const float* Wq  = (const float*)d_in[1];
  const float* bq  = (const float*)d_in[2];
  const float* Wk  = (const float*)d_in[3];
  const float* bk  = (const float*)d_in[4];
  const float* wg  = (const float*)d_in[5];
  const float* Wp  = (const float*)d_in[6];
  const float* bp  = (const float*)d_in[7];
  const float* Wf  = (const float*)d_in[8];
  const float* bfv = (const float*)d_in[9];
  float* out = (float*)d_out;
  char* ws = (char*)d_ws;

  const size_t SZQN = (size_t)64 * 784 * 512 * 2;   // 51,380,224 B
  __bf16* Qn   = (__bf16*)(ws);
  __bf16* Kn   = (__bf16*)(ws + SZQN);
  __bf16* WqT  = (__bf16*)(ws + 2 * SZQN);
  __bf16* WkT  = (__bf16*)(ws + 2 * SZQN + 524288);
  __bf16* WcT  = (__bf16*)(ws + 2 * SZQN + 2 * 524288);
  float*  bpf  = (float*) (ws + 2 * SZQN + 2 * 524288 + 1048576);
  float*  pctx = (float*) (ws + 2 * SZQN + 2 * 524288 + 1048576 + 2048);
  float*  pgsq = (float*) (ws + 2 * SZQN + 2 * 524288 + 1048576 + 2048 + 1703936);
  float*  ctx  = (float*) (ws + 2 * SZQN + 2 * 524288 + 1048576 + 2048 + 1703936 + 4096);
  // total ~106.8 MB

  k_prep_t<<<dim3(16, 16),    dim3(32, 8), 0, stream>>>(Wq, Wk, WqT, WkT);
  k_prep_w<<<dim3(512),       dim3(512),   0, stream>>>(Wp, Wf, bp, bfv, WcT, bpf);
  k_qk    <<<dim3(26, 64),    dim3(512),   0, stream>>>(x, WqT, WkT, bq, bk, wg, Qn, Kn, pctx, pgsq);
  k_ctx2  <<<dim3(64),        dim3(512),   0, stream>>>(pctx, pgsq, ctx);
  k_out   <<<dim3(13, 2, 64), dim3(256),   0, stream>>>(Qn, Kn, ctx, WcT, bpf, out);
}

// Round 8
// 411.294 us; speedup vs baseline: 1.0893x; 1.0893x over previous
//
#include <hip/hip_runtime.h>

#define EPSN 1e-12f
#define SCALE_F 0.044194173824159216f  // 512^-0.5
#define MTOT 50176

typedef __bf16 bf16x8 __attribute__((ext_vector_type(8)));
typedef __bf16 bf16x4 __attribute__((ext_vector_type(4)));
typedef float  f32x4  __attribute__((ext_vector_type(4)));

__device__ __forceinline__ void gld16(const void* src, void* dst) {
  __builtin_amdgcn_global_load_lds(
      (const __attribute__((address_space(1))) unsigned int*)src,
      (__attribute__((address_space(3))) unsigned int*)dst, 16, 0, 0);
}

// ---------------- prep: WqT/WkT bf16 [d][c] = W[c][d], LDS tile transpose ----------------
__global__ __launch_bounds__(256) void k_prep_t(const float* __restrict__ Wq,
                                                const float* __restrict__ Wk,
                                                __bf16* __restrict__ WqT,
                                                __bf16* __restrict__ WkT) {
  __shared__ float Tq[32][33], Tk[32][33];
  const int c0 = blockIdx.x * 32, d0 = blockIdx.y * 32;
  const int dx = threadIdx.x, cy = threadIdx.y;  // 32, 8
  #pragma unroll
  for (int p = 0; p < 4; ++p) {
    int c = cy + p * 8;
    Tq[c][dx] = Wq[(size_t)(c0 + c) * 512 + d0 + dx];
    Tk[c][dx] = Wk[(size_t)(c0 + c) * 512 + d0 + dx];
  }
  __syncthreads();
  #pragma unroll
  for (int p = 0; p < 4; ++p) {
    int d = cy + p * 8;
    WqT[(size_t)(d0 + d) * 512 + c0 + dx] = (__bf16)Tq[dx][d];
    WkT[(size_t)(d0 + d) * 512 + c0 + dx] = (__bf16)Tk[dx][d];
  }
}

// ---- prep: WcT[d][kk]: kk<512 -> (Wp@Wf)[kk][d]; kk>=512 -> Wf[kk-512][d]. bpf[d]=bp@Wf+bf
// 64 blocks x 8 kk-rows each: Wf traffic /8.
__global__ __launch_bounds__(512) void k_prep_w(const float* __restrict__ Wp,
                                                const float* __restrict__ Wf,
                                                const float* __restrict__ bp,
                                                const float* __restrict__ bfv,
                                                __bf16* __restrict__ WcT,
                                                float* __restrict__ bpf) {
  const int kk0 = blockIdx.x * 8;
  const int d = threadIdx.x;
  float acc[8] = {};
  float bacc = 0.f;
  const bool dobp = (blockIdx.x == 0);
  for (int c = 0; c < 512; ++c) {
    float wf = Wf[(size_t)c * 512 + d];
    #pragma unroll
    for (int i = 0; i < 8; ++i) acc[i] = fmaf(Wp[(size_t)(kk0 + i) * 512 + c], wf, acc[i]);
    if (dobp) bacc = fmaf(bp[c], wf, bacc);
  }
  #pragma unroll
  for (int i = 0; i < 8; ++i) {
    WcT[(size_t)d * 1024 + kk0 + i]       = (__bf16)acc[i];
    WcT[(size_t)d * 1024 + 512 + kk0 + i] = (__bf16)Wf[(size_t)(kk0 + i) * 512 + d];
  }
  if (dobp) bpf[d] = bacc + bfv[d];
}

// ---------------- Q/K GEMM (m97 geometry): 128x128 tile, 256 thr, 16KB LDS, BK=32 ----------------
// grid: 3584 1D, XCD-swizzled. p -> (b, mt) group of 8 members (qk, nt).
// Epilogue: +bias, store raw bf16, per-64col partial sumsq & g-dot.
__global__ __launch_bounds__(256, 3) void k_gemm(const float* __restrict__ x,
                                                 const __bf16* __restrict__ WqT,
                                                 const __bf16* __restrict__ WkT,
                                                 const float* __restrict__ bq,
                                                 const float* __restrict__ bk,
                                                 const float* __restrict__ wg,
                                                 __bf16* __restrict__ qraw,
                                                 __bf16* __restrict__ kraw,
                                                 float* __restrict__ psqQ,
                                                 float* __restrict__ psqK,
                                                 float* __restrict__ gdo) {
  __shared__ __align__(1024) unsigned char As[8192], Bs[8192];
  const int t = threadIdx.x, l = t & 63, w = t >> 6;
  const int li = l & 15, lq = l >> 4;
  // decode XCD-swizzled id: p = ((g>>3)*8 + m)*8 + (g&7)
  const int p = blockIdx.x;
  const int xq = p & 7, q2 = p >> 3;
  const int m8 = q2 & 7;
  const int g = (q2 >> 3) * 8 + xq;       // 0..447
  const int b = g / 7, mt = g % 7;
  const int qk = m8 >> 2, nt = m8 & 3;
  const int m0 = mt * 128;
  const __bf16* Wt = qk ? WkT : WqT;

  // A staging: wave w stages regions 2w, 2w+1; lane l -> (row li, k-oct lq)
  const int r0 = 2 * w, r1 = r0 + 1;
  int row0 = m0 + r0 * 16 + li; if (row0 > 783) row0 = 783;
  int row1 = m0 + r1 * 16 + li; if (row1 > 783) row1 = 783;
  const float* xp0 = x + ((size_t)b * 512 + lq * 8) * 784 + row0;
  const float* xp1 = x + ((size_t)b * 512 + lq * 8) * 784 + row1;
  // B staging src (gld16): lane l -> (row li, k-oct lq), 64B contiguous per row
  const __bf16* wp0 = Wt + (size_t)(nt * 128 + r0 * 16 + li) * 512 + lq * 8;
  const __bf16* wp1 = Wt + (size_t)(nt * 128 + r1 * 16 + li) * 512 + lq * 8;

  f32x4 acc[4][4] = {};

  for (int ks = 0; ks < 16; ++ks) {
    const int k0 = ks * 32;
    gld16(wp0 + k0, Bs + r0 * 1024);
    gld16(wp1 + k0, Bs + r1 * 1024);
    {
      float v0[8], v1[8];
      #pragma unroll
      for (int j = 0; j < 8; ++j) v0[j] = xp0[(size_t)(k0 + j) * 784];
      #pragma unroll
      for (int j = 0; j < 8; ++j) v1[j] = xp1[(size_t)(k0 + j) * 784];
      bf16x8 a0, a1;
      #pragma unroll
      for (int j = 0; j < 8; ++j) { a0[j] = (__bf16)v0[j]; a1[j] = (__bf16)v1[j]; }
      *(bf16x8*)(As + r0 * 1024 + l * 16) = a0;
      *(bf16x8*)(As + r1 * 1024 + l * 16) = a1;
    }
    __syncthreads();
    bf16x8 af[4];
    #pragma unroll
    for (int rb = 0; rb < 4; ++rb)
      af[rb] = *(const bf16x8*)(As + ((w & 1) * 4 + rb) * 1024 + l * 16);
    #pragma unroll
    for (int cb = 0; cb < 4; ++cb) {
      bf16x8 bf = *(const bf16x8*)(Bs + ((w >> 1) * 4 + cb) * 1024 + l * 16);
      #pragma unroll
      for (int rb = 0; rb < 4; ++rb)
        acc[rb][cb] = __builtin_amdgcn_mfma_f32_16x16x32_bf16(af[rb], bf, acc[rb][cb], 0, 0, 0);
    }
    __syncthreads();
  }

  // epilogue: bias, raw store, per-colgroup partial sumsq (+ gdot for Q)
  const float* bias = qk ? bk : bq;
  __bf16* dst = qk ? kraw : qraw;
  float* psq = qk ? psqK : psqQ;
  const int colb = nt * 128 + (w >> 1) * 64;
  const int cg = nt * 2 + (w >> 1);
  float bv[4], wv[4];
  #pragma unroll
  for (int cb = 0; cb < 4; ++cb) {
    int col = colb + cb * 16 + li;
    bv[cb] = bias[col];
    wv[cb] = qk ? 0.f : wg[col];
  }
  #pragma unroll
  for (int rb = 0; rb < 4; ++rb)
    #pragma unroll
    for (int j = 0; j < 4; ++j) {
      int rowg = m0 + (w & 1) * 64 + rb * 16 + lq * 4 + j;
      bool ok = rowg < 784;
      size_t token = (size_t)b * 784 + rowg;
      float ss = 0.f, sg = 0.f;
      #pragma unroll
      for (int cb = 0; cb < 4; ++cb) {
        float v = acc[rb][cb][j] + bv[cb];
        ss = fmaf(v, v, ss);
        sg = fmaf(v, wv[cb], sg);
        if (ok) dst[token * 512 + colb + cb * 16 + li] = (__bf16)v;
      }
      ss += __shfl_xor(ss, 1); ss += __shfl_xor(ss, 2); ss += __shfl_xor(ss, 4); ss += __shfl_xor(ss, 8);
      sg += __shfl_xor(sg, 1); sg += __shfl_xor(sg, 2); sg += __shfl_xor(sg, 4); sg += __shfl_xor(sg, 8);
      if (ok && li == 0) {
        psq[(size_t)cg * MTOT + token] = ss;
        if (!qk) gdo[(size_t)cg * MTOT + token] = sg;
      }
    }
}

// ---------------- per-token combine: invq, invk, coef, g ----------------
__global__ __launch_bounds__(256) void k_normc(const float* __restrict__ psqQ,
                                               const float* __restrict__ psqK,
                                               const float* __restrict__ gdo,
                                               float* __restrict__ invqA,
                                               float* __restrict__ invkA,
                                               float* __restrict__ coefA,
                                               float* __restrict__ gA) {
  const int tkn = blockIdx.x * 256 + threadIdx.x;
  if (tkn >= MTOT) return;
  float sq = 0.f, sk = 0.f, gd = 0.f;
  #pragma unroll
  for (int cg = 0; cg < 8; ++cg) {
    sq += psqQ[(size_t)cg * MTOT + tkn];
    sk += psqK[(size_t)cg * MTOT + tkn];
    gd += gdo[(size_t)cg * MTOT + tkn];
  }
  float invq = 1.f / fmaxf(sqrtf(sq), EPSN);
  float invk = 1.f / fmaxf(sqrtf(sk), EPSN);
  float gv = gd * invq;
  invqA[tkn] = invq;
  invkA[tkn] = invk;
  coefA[tkn] = gv * invq;
  gA[tkn]    = gv;
}

// ---------------- per-batch: ||g|| + ctx[d] = alpha * sum_n coef[n]*qraw[n,d] ----------------
__global__ __launch_bounds__(512) void k_pctx(const __bf16* __restrict__ qraw,
                                              const float* __restrict__ coefA,
                                              const float* __restrict__ gA,
                                              float* __restrict__ ctx) {
  __shared__ float wred[8];
  const int b = blockIdx.x, t = threadIdx.x;
  const size_t base = (size_t)b * 784;
  float gsq = 0.f;
  { float gv = gA[base + t]; gsq = gv * gv; }               // t < 512 < 784
  if (t + 512 < 784) { float gv = gA[base + t + 512]; gsq = fmaf(gv, gv, gsq); }
  gsq += __shfl_xor(gsq, 1);  gsq += __shfl_xor(gsq, 2);  gsq += __shfl_xor(gsq, 4);
  gsq += __shfl_xor(gsq, 8);  gsq += __shfl_xor(gsq, 16); gsq += __shfl_xor(gsq, 32);
  if ((t & 63) == 0) wred[t >> 6] = gsq;
  __syncthreads();
  float tot = 0.f;
  #pragma unroll
  for (int i = 0; i < 8; ++i) tot += wred[i];
  const float alpha = SCALE_F / fmaxf(sqrtf(tot) * SCALE_F, EPSN);
  float a0 = 0.f, a1 = 0.f, a2 = 0.f, a3 = 0.f;
  for (int n = 0; n < 784; n += 4) {
    a0 = fmaf(coefA[base + n],     (float)qraw[(base + n) * 512 + t],     a0);
    a1 = fmaf(coefA[base + n + 1], (float)qraw[(base + n + 1) * 512 + t], a1);
    a2 = fmaf(coefA[base + n + 2], (float)qraw[(base + n + 2) * 512 + t], a2);
    a3 = fmaf(coefA[base + n + 3], (float)qraw[(base + n + 3) * 512 + t], a3);
  }
  ctx[(size_t)b * 512 + t] = alpha * ((a0 + a1) + (a2 + a3));
}

// ---------------- final GEMM (m97 geometry): out = ([ctx.(kraw.invk) | qraw.invq] @ WcT^T + bpf)^T
__global__ __launch_bounds__(256, 3) void k_out(const __bf16* __restrict__ qraw,
                                                const __bf16* __restrict__ kraw,
                                                const float* __restrict__ invqA,
                                                const float* __restrict__ invkA,
                                                const float* __restrict__ ctx,
                                                const __bf16* __restrict__ WcT,
                                                const float* __restrict__ bpf,
                                                float* __restrict__ out) {
  __shared__ __align__(1024) unsigned char As[8192], Bs[8192];
  __shared__ float ctx_l[512];
  const int t = threadIdx.x, l = t & 63, w = t >> 6;
  const int li = l & 15, lq = l >> 4;
  // decode XCD-swizzled id: p = ((g>>3)*4 + m)*8 + (g&7)
  const int p = blockIdx.x;
  const int xq = p & 7, q2 = p >> 3;
  const int nt = q2 & 3;
  const int g = (q2 >> 2) * 8 + xq;       // 0..447
  const int b = g / 7, mt = g % 7;
  const int m0 = mt * 128;

  ctx_l[t]       = ctx[(size_t)b * 512 + t];
  ctx_l[t + 256] = ctx[(size_t)b * 512 + t + 256];

  // A staging: thread stages chunk l of regions w and w+4
  const int rA0 = w, rA1 = w + 4;
  int row0 = m0 + rA0 * 16 + li; if (row0 > 783) row0 = 783;
  int row1 = m0 + rA1 * 16 + li; if (row1 > 783) row1 = 783;
  const size_t tk0 = (size_t)b * 784 + row0, tk1 = (size_t)b * 784 + row1;
  const float iq0 = invqA[tk0], ik0 = invkA[tk0];
  const float iq1 = invqA[tk1], ik1 = invkA[tk1];
  // B staging src (gld16), regions 2w, 2w+1
  const __bf16* wpB0 = WcT + (size_t)(nt * 128 + (2 * w) * 16 + li) * 1024 + lq * 8;
  const __bf16* wpB1 = WcT + (size_t)(nt * 128 + (2 * w + 1) * 16 + li) * 1024 + lq * 8;

  f32x4 acc[4][4] = {};
  __syncthreads();   // ctx_l ready

  for (int ks = 0; ks < 32; ++ks) {
    const int k0 = ks * 32;
    gld16(wpB0 + k0, Bs + (2 * w) * 1024);
    gld16(wpB1 + k0, Bs + (2 * w + 1) * 1024);
    {
      const bool dk = ks < 16;
      const __bf16* ap = dk ? kraw : qraw;
      const int kk = (k0 & 511) + lq * 8;
      bf16x8 v0 = *(const bf16x8*)(ap + tk0 * 512 + kk);
      bf16x8 v1 = *(const bf16x8*)(ap + tk1 * 512 + kk);
      const float s0 = dk ? ik0 : iq0, s1 = dk ? ik1 : iq1;
      bf16x8 o0, o1;
      if (dk) {
        f32x4 c0 = *(const f32x4*)&ctx_l[kk];
        f32x4 c1 = *(const f32x4*)&ctx_l[kk + 4];
        #pragma unroll
        for (int j = 0; j < 4; ++j) {
          o0[j]     = (__bf16)((float)v0[j]     * s0 * c0[j]);
          o0[4 + j] = (__bf16)((float)v0[4 + j] * s0 * c1[j]);
          o1[j]     = (__bf16)((float)v1[j]     * s1 * c0[j]);
          o1[4 + j] = (__bf16)((float)v1[4 + j] * s1 * c1[j]);
        }
      } else {
        #pragma unroll
        for (int j = 0; j < 8; ++j) {
          o0[j] = (__bf16)((float)v0[j] * s0);
          o1[j] = (__bf16)((float)v1[j] * s1);
        }
      }
      *(bf16x8*)(As + rA0 * 1024 + l * 16) = o0;
      *(bf16x8*)(As + rA1 * 1024 + l * 16) = o1;
    }
    __syncthreads();
    bf16x8 af[4];
    #pragma unroll
    for (int rb = 0; rb < 4; ++rb)
      af[rb] = *(const bf16x8*)(As + ((w & 1) * 4 + rb) * 1024 + l * 16);
    #pragma unroll
    for (int cb = 0; cb < 4; ++cb) {
      bf16x8 bf = *(const bf16x8*)(Bs + ((w >> 1) * 4 + cb) * 1024 + l * 16);
      #pragma unroll
      for (int rb = 0; rb < 4; ++rb)
        acc[rb][cb] = __builtin_amdgcn_mfma_f32_16x16x32_bf16(af[rb], bf, acc[rb][cb], 0, 0, 0);
    }
    __syncthreads();
  }

  // epilogue: + bias, transposed coalesced f32x4 stores
  const int colb = nt * 128 + (w >> 1) * 64;
  float bv[4];
  #pragma unroll
  for (int cb = 0; cb < 4; ++cb) bv[cb] = bpf[colb + cb * 16 + li];
  #pragma unroll
  for (int rb = 0; rb < 4; ++rb) {
    int nrow = m0 + (w & 1) * 64 + rb * 16 + lq * 4;
    if (nrow < 784) {
      #pragma unroll
      for (int cb = 0; cb < 4; ++cb) {
        f32x4 v;
        #pragma unroll
        for (int j = 0; j < 4; ++j) v[j] = acc[rb][cb][j] + bv[cb];
        *(f32x4*)&out[((size_t)b * 512 + colb + cb * 16 + li) * 784 + nrow] = v;
      }
    }
  }
}

extern "C" void kernel_launch(void* const* d_in, const int* in_sizes, int n_in,
                              void* d_out, int out_size, void* d_ws, size_t ws_size,
                              hipStream_t stream) {
  const float* x   = (const float*)d_in[0];
  const float* Wq  = (const float*)d_in[1];
  const float* bq  = (const float*)d_in[2];
  const float* Wk  = (const float*)d_in[3];
  const float* bk  = (const float*)d_in[4];
  const float* wg  = (const float*)d_in[5];
  const float* Wp  = (const float*)d_in[6];
  const float* bp  = (const float*)d_in[7];
  const float* Wf  = (const float*)d_in[8];
  const float* bfv = (const float*)d_in[9];
  float* out = (float*)d_out;
  char* ws = (char*)d_ws;

  const size_t SZRAW = (size_t)MTOT * 512 * 2;        // 51,380,224 B
  size_t off = 0;
  __bf16* qraw = (__bf16*)(ws + off); off += SZRAW;
  __bf16* kraw = (__bf16*)(ws + off); off += SZRAW;
  __bf16* WqT  = (__bf16*)(ws + off); off += 524288;
  __bf16* WkT  = (__bf16*)(ws + off); off += 524288;
  __bf16* WcT  = (__bf16*)(ws + off); off += 1048576;
  float*  bpf  = (float*) (ws + off); off += 2048;
  float*  psqQ = (float*) (ws + off); off += (size_t)8 * MTOT * 4;
  float*  psqK = (float*) (ws + off); off += (size_t)8 * MTOT * 4;
  float*  gdo  = (float*) (ws + off); off += (size_t)8 * MTOT * 4;
  float*  invqA = (float*)(ws + off); off += (size_t)MTOT * 4;
  float*  invkA = (float*)(ws + off); off += (size_t)MTOT * 4;
  float*  coefA = (float*)(ws + off); off += (size_t)MTOT * 4;
  float*  gA    = (float*)(ws + off); off += (size_t)MTOT * 4;
  float*  ctx   = (float*)(ws + off); off += 131072;
  // total ~110.6 MB

  k_prep_t<<<dim3(16, 16), dim3(32, 8), 0, stream>>>(Wq, Wk, WqT, WkT);
  k_prep_w<<<dim3(64),     dim3(512),   0, stream>>>(Wp, Wf, bp, bfv, WcT, bpf);
  k_gemm  <<<dim3(3584),   dim3(256),   0, stream>>>(x, WqT, WkT, bq, bk, wg,
                                                     qraw, kraw, psqQ, psqK, gdo);
  k_normc <<<dim3(196),    dim3(256),   0, stream>>>(psqQ, psqK, gdo, invqA, invkA, coefA, gA);
  k_pctx  <<<dim3(64),     dim3(512),   0, stream>>>(qraw, coefA, gA, ctx);
  k_out   <<<dim3(1792),   dim3(256),   0, stream>>>(qraw, kraw, invqA, invkA, ctx, WcT, bpf, out);
}

// Round 9
// 408.759 us; speedup vs baseline: 1.0961x; 1.0062x over previous
//
#include <hip/hip_runtime.h>

#define EPSN 1e-12f
#define SCALE_F 0.044194173824159216f  // 512^-0.5
#define MTOT 50176

typedef __bf16 bf16x8 __attribute__((ext_vector_type(8)));
typedef float  f32x4  __attribute__((ext_vector_type(4)));

__device__ __forceinline__ void gld16(const void* src, void* dst) {
  __builtin_amdgcn_global_load_lds(
      (const __attribute__((address_space(1))) unsigned int*)src,
      (__attribute__((address_space(3))) unsigned int*)dst, 16, 0, 0);
}

// ---------------- prep: xT[bl][n][c] = bf16(x[b0+bl][c][n]) ----------------
__global__ __launch_bounds__(256) void k_xt(const float* __restrict__ x,
                                            __bf16* __restrict__ xT, int b0) {
  __shared__ float T[32][33];
  const int n0 = blockIdx.x * 32, c0 = blockIdx.y * 32;
  const int bl = blockIdx.z, b = b0 + bl;
  const int dx = threadIdx.x, ty = threadIdx.y;   // 32, 8
  #pragma unroll
  for (int pp = 0; pp < 4; ++pp) {
    int c = ty + pp * 8;
    int n = n0 + dx;
    T[c][dx] = (n < 784) ? x[((size_t)b * 512 + c0 + c) * 784 + n] : 0.f;
  }
  __syncthreads();
  #pragma unroll
  for (int pp = 0; pp < 4; ++pp) {
    int n = ty + pp * 8;
    if (n0 + n < 784)
      xT[((size_t)bl * 784 + n0 + n) * 512 + c0 + dx] = (__bf16)T[dx][n];
  }
}

// ---------------- prep: WqT/WkT bf16 [d][c] = W[c][d], LDS tile transpose ----------------
__global__ __launch_bounds__(256) void k_prep_t(const float* __restrict__ Wq,
                                                const float* __restrict__ Wk,
                                                __bf16* __restrict__ WqT,
                                                __bf16* __restrict__ WkT) {
  __shared__ float Tq[32][33], Tk[32][33];
  const int c0 = blockIdx.x * 32, d0 = blockIdx.y * 32;
  const int dx = threadIdx.x, cy = threadIdx.y;  // 32, 8
  #pragma unroll
  for (int p = 0; p < 4; ++p) {
    int c = cy + p * 8;
    Tq[c][dx] = Wq[(size_t)(c0 + c) * 512 + d0 + dx];
    Tk[c][dx] = Wk[(size_t)(c0 + c) * 512 + d0 + dx];
  }
  __syncthreads();
  #pragma unroll
  for (int p = 0; p < 4; ++p) {
    int d = cy + p * 8;
    WqT[(size_t)(d0 + d) * 512 + c0 + dx] = (__bf16)Tq[dx][d];
    WkT[(size_t)(d0 + d) * 512 + c0 + dx] = (__bf16)Tk[dx][d];
  }
}

// ---- prep: WcT[d][kk]: kk<512 -> (Wp@Wf)[kk][d]; kk>=512 -> Wf[kk-512][d]. bpf[d]=bp@Wf+bf
__global__ __launch_bounds__(512) void k_prep_w(const float* __restrict__ Wp,
                                                const float* __restrict__ Wf,
                                                const float* __restrict__ bp,
                                                const float* __restrict__ bfv,
                                                __bf16* __restrict__ WcT,
                                                float* __restrict__ bpf) {
  const int kk0 = blockIdx.x * 8;
  const int d = threadIdx.x;
  float acc[8] = {};
  float bacc = 0.f;
  const bool dobp = (blockIdx.x == 0);
  for (int c = 0; c < 512; ++c) {
    float wf = Wf[(size_t)c * 512 + d];
    #pragma unroll
    for (int i = 0; i < 8; ++i) acc[i] = fmaf(Wp[(size_t)(kk0 + i) * 512 + c], wf, acc[i]);
    if (dobp) bacc = fmaf(bp[c], wf, bacc);
  }
  #pragma unroll
  for (int i = 0; i < 8; ++i) {
    WcT[(size_t)d * 1024 + kk0 + i]       = (__bf16)acc[i];
    WcT[(size_t)d * 1024 + 512 + kk0 + i] = (__bf16)Wf[(size_t)(kk0 + i) * 512 + d];
  }
  if (dobp) bpf[d] = bacc + bfv[d];
}

// ---------------- merged Q+K GEMM: 128 tok x 128 d, all-gld16 staging ----------------
// One A-tile (xT) feeds both Q and K MFMAs. grid 896/slice, XCD-swizzled so the
// 4 nt-members of a (b,mt) group share A in one XCD's L2.
__global__ __launch_bounds__(256, 2) void k_gemm(const __bf16* __restrict__ xT,
                                                 const __bf16* __restrict__ WqT,
                                                 const __bf16* __restrict__ WkT,
                                                 const float* __restrict__ bq,
                                                 const float* __restrict__ bk,
                                                 const float* __restrict__ wg,
                                                 const int b0,
                                                 __bf16* __restrict__ qraw,
                                                 __bf16* __restrict__ kraw,
                                                 float* __restrict__ psqQ,
                                                 float* __restrict__ psqK,
                                                 float* __restrict__ gdo) {
  __shared__ __align__(1024) unsigned char As[8192], BQs[8192], BKs[8192];
  const int t = threadIdx.x, l = t & 63, w = t >> 6;
  const int li = l & 15, lq = l >> 4;
  // decode: p = ((Gq*4 + nt)<<3) | xq ; g = Gq*8 + xq  (members share xq -> same XCD)
  const int p = blockIdx.x;
  const int xq = p & 7, q2 = p >> 3;
  const int nt = q2 & 3;
  const int g = (q2 >> 2) * 8 + xq;       // 0..223
  const int bl = g / 7, mt = g % 7;
  const int b = b0 + bl;
  const int m0 = mt * 128;

  const int r0 = 2 * w, r1 = r0 + 1;
  int row0 = m0 + r0 * 16 + li; if (row0 > 783) row0 = 783;
  int row1 = m0 + r1 * 16 + li; if (row1 > 783) row1 = 783;
  const __bf16* a0s = xT + ((size_t)bl * 784 + row0) * 512 + lq * 8;
  const __bf16* a1s = xT + ((size_t)bl * 784 + row1) * 512 + lq * 8;
  const __bf16* q0s = WqT + (size_t)(nt * 128 + r0 * 16 + li) * 512 + lq * 8;
  const __bf16* q1s = WqT + (size_t)(nt * 128 + r1 * 16 + li) * 512 + lq * 8;
  const __bf16* k0s = WkT + (size_t)(nt * 128 + r0 * 16 + li) * 512 + lq * 8;
  const __bf16* k1s = WkT + (size_t)(nt * 128 + r1 * 16 + li) * 512 + lq * 8;

  f32x4 accQ[4][4] = {}, accK[4][4] = {};

  for (int ks = 0; ks < 16; ++ks) {
    const int k0 = ks * 32;
    gld16(a0s + k0, As + r0 * 1024);
    gld16(a1s + k0, As + r1 * 1024);
    gld16(q0s + k0, BQs + r0 * 1024);
    gld16(q1s + k0, BQs + r1 * 1024);
    gld16(k0s + k0, BKs + r0 * 1024);
    gld16(k1s + k0, BKs + r1 * 1024);
    __syncthreads();
    bf16x8 af[4];
    #pragma unroll
    for (int rb = 0; rb < 4; ++rb)
      af[rb] = *(const bf16x8*)(As + ((w & 1) * 4 + rb) * 1024 + l * 16);
    #pragma unroll
    for (int cb = 0; cb < 4; ++cb) {
      bf16x8 bq8 = *(const bf16x8*)(BQs + ((w >> 1) * 4 + cb) * 1024 + l * 16);
      #pragma unroll
      for (int rb = 0; rb < 4; ++rb)
        accQ[rb][cb] = __builtin_amdgcn_mfma_f32_16x16x32_bf16(af[rb], bq8, accQ[rb][cb], 0, 0, 0);
      bf16x8 bk8 = *(const bf16x8*)(BKs + ((w >> 1) * 4 + cb) * 1024 + l * 16);
      #pragma unroll
      for (int rb = 0; rb < 4; ++rb)
        accK[rb][cb] = __builtin_amdgcn_mfma_f32_16x16x32_bf16(af[rb], bk8, accK[rb][cb], 0, 0, 0);
    }
    __syncthreads();
  }

  // epilogue: bias, raw stores, per-colgroup partial sumsq (Q,K) + gdot (Q)
  const int colb = nt * 128 + (w >> 1) * 64;
  const int cg = nt * 2 + (w >> 1);
  float bqv[4], bkv[4], wv[4];
  #pragma unroll
  for (int cb = 0; cb < 4; ++cb) {
    int col = colb + cb * 16 + li;
    bqv[cb] = bq[col]; bkv[cb] = bk[col]; wv[cb] = wg[col];
  }
  #pragma unroll
  for (int rb = 0; rb < 4; ++rb)
    #pragma unroll
    for (int j = 0; j < 4; ++j) {
      int rowg = m0 + (w & 1) * 64 + rb * 16 + lq * 4 + j;
      bool ok = rowg < 784;
      size_t token = (size_t)b * 784 + rowg;
      float ssq = 0.f, ssk = 0.f, sg = 0.f;
      #pragma unroll
      for (int cb = 0; cb < 4; ++cb) {
        float vq = accQ[rb][cb][j] + bqv[cb];
        float vk = accK[rb][cb][j] + bkv[cb];
        ssq = fmaf(vq, vq, ssq);
        ssk = fmaf(vk, vk, ssk);
        sg  = fmaf(vq, wv[cb], sg);
        if (ok) {
          qraw[token * 512 + colb + cb * 16 + li] = (__bf16)vq;
          kraw[token * 512 + colb + cb * 16 + li] = (__bf16)vk;
        }
      }
      ssq += __shfl_xor(ssq, 1); ssq += __shfl_xor(ssq, 2); ssq += __shfl_xor(ssq, 4); ssq += __shfl_xor(ssq, 8);
      ssk += __shfl_xor(ssk, 1); ssk += __shfl_xor(ssk, 2); ssk += __shfl_xor(ssk, 4); ssk += __shfl_xor(ssk, 8);
      sg  += __shfl_xor(sg, 1);  sg  += __shfl_xor(sg, 2);  sg  += __shfl_xor(sg, 4);  sg  += __shfl_xor(sg, 8);
      if (ok && li == 0) {
        psqQ[(size_t)cg * MTOT + token] = ssq;
        psqK[(size_t)cg * MTOT + token] = ssk;
        gdo [(size_t)cg * MTOT + token] = sg;
      }
    }
}

// ---------------- per-token combine: invq, invk, coef, g ----------------
__global__ __launch_bounds__(256) void k_normc(const float* __restrict__ psqQ,
                                               const float* __restrict__ psqK,
                                               const float* __restrict__ gdo,
                                               float* __restrict__ invqA,
                                               float* __restrict__ invkA,
                                               float* __restrict__ coefA,
                                               float* __restrict__ gA) {
  const int tkn = blockIdx.x * 256 + threadIdx.x;
  if (tkn >= MTOT) return;
  float sq = 0.f, sk = 0.f, gd = 0.f;
  #pragma unroll
  for (int cg = 0; cg < 8; ++cg) {
    sq += psqQ[(size_t)cg * MTOT + tkn];
    sk += psqK[(size_t)cg * MTOT + tkn];
    gd += gdo[(size_t)cg * MTOT + tkn];
  }
  float invq = 1.f / fmaxf(sqrtf(sq), EPSN);
  float invk = 1.f / fmaxf(sqrtf(sk), EPSN);
  float gv = gd * invq;
  invqA[tkn] = invq;
  invkA[tkn] = invk;
  coefA[tkn] = gv * invq;
  gA[tkn]    = gv;
}

// ---------------- per-batch: ||g|| + ctx[d] = alpha * sum_n coef[n]*qraw[n,d] ----------------
// grid (4 d-chunks, 64 b); 4 n-strips per chunk reduced in fixed order (deterministic).
__global__ __launch_bounds__(512) void k_pctx(const __bf16* __restrict__ qraw,
                                              const float* __restrict__ coefA,
                                              const float* __restrict__ gA,
                                              float* __restrict__ ctx) {
  __shared__ float wred[8];
  __shared__ float part[4][128];
  const int ch = blockIdx.x, b = blockIdx.y, t = threadIdx.x;
  const size_t base = (size_t)b * 784;
  float gsq;
  { float gv = gA[base + t]; gsq = gv * gv; }
  if (t + 512 < 784) { float gv = gA[base + t + 512]; gsq = fmaf(gv, gv, gsq); }
  gsq += __shfl_xor(gsq, 1);  gsq += __shfl_xor(gsq, 2);  gsq += __shfl_xor(gsq, 4);
  gsq += __shfl_xor(gsq, 8);  gsq += __shfl_xor(gsq, 16); gsq += __shfl_xor(gsq, 32);
  if ((t & 63) == 0) wred[t >> 6] = gsq;
  __syncthreads();
  float tot = 0.f;
  #pragma unroll
  for (int i = 0; i < 8; ++i) tot += wred[i];
  const float alpha = SCALE_F / fmaxf(sqrtf(tot) * SCALE_F, EPSN);
  const int dof = t & 127, s = t >> 7;
  const int nb = s * 196;
  const __bf16* qb = qraw + (base + nb) * 512 + ch * 128 + dof;
  const float* cf = coefA + base + nb;
  float a0 = 0.f, a1 = 0.f, a2 = 0.f, a3 = 0.f;
  for (int n = 0; n < 196; n += 4) {
    a0 = fmaf(cf[n],     (float)qb[(size_t)n * 512],       a0);
    a1 = fmaf(cf[n + 1], (float)qb[(size_t)(n + 1) * 512], a1);
    a2 = fmaf(cf[n + 2], (float)qb[(size_t)(n + 2) * 512], a2);
    a3 = fmaf(cf[n + 3], (float)qb[(size_t)(n + 3) * 512], a3);
  }
  part[s][dof] = (a0 + a1) + (a2 + a3);
  __syncthreads();
  if (t < 128) {
    float sum = part[0][t] + part[1][t] + part[2][t] + part[3][t];
    ctx[(size_t)b * 512 + ch * 128 + t] = alpha * sum;
  }
}

// ---------------- final GEMM (m97 geometry): out = ([ctx.(kraw.invk) | qraw.invq] @ WcT^T + bpf)^T
__global__ __launch_bounds__(256, 3) void k_out(const __bf16* __restrict__ qraw,
                                                const __bf16* __restrict__ kraw,
                                                const float* __restrict__ invqA,
                                                const float* __restrict__ invkA,
                                                const float* __restrict__ ctx,
                                                const __bf16* __restrict__ WcT,
                                                const float* __restrict__ bpf,
                                                float* __restrict__ out) {
  __shared__ __align__(1024) unsigned char As[8192], Bs[8192];
  __shared__ float ctx_l[512];
  const int t = threadIdx.x, l = t & 63, w = t >> 6;
  const int li = l & 15, lq = l >> 4;
  const int p = blockIdx.x;
  const int xq = p & 7, q2 = p >> 3;
  const int nt = q2 & 3;
  const int g = (q2 >> 2) * 8 + xq;       // 0..447
  const int b = g / 7, mt = g % 7;
  const int m0 = mt * 128;

  ctx_l[t]       = ctx[(size_t)b * 512 + t];
  ctx_l[t + 256] = ctx[(size_t)b * 512 + t + 256];

  const int rA0 = w, rA1 = w + 4;
  int row0 = m0 + rA0 * 16 + li; if (row0 > 783) row0 = 783;
  int row1 = m0 + rA1 * 16 + li; if (row1 > 783) row1 = 783;
  const size_t tk0 = (size_t)b * 784 + row0, tk1 = (size_t)b * 784 + row1;
  const float iq0 = invqA[tk0], ik0 = invkA[tk0];
  const float iq1 = invqA[tk1], ik1 = invkA[tk1];
  const __bf16* wpB0 = WcT + (size_t)(nt * 128 + (2 * w) * 16 + li) * 1024 + lq * 8;
  const __bf16* wpB1 = WcT + (size_t)(nt * 128 + (2 * w + 1) * 16 + li) * 1024 + lq * 8;

  f32x4 acc[4][4] = {};
  __syncthreads();   // ctx_l ready

  for (int ks = 0; ks < 32; ++ks) {
    const int k0 = ks * 32;
    gld16(wpB0 + k0, Bs + (2 * w) * 1024);
    gld16(wpB1 + k0, Bs + (2 * w + 1) * 1024);
    {
      const bool dk = ks < 16;
      const __bf16* ap = dk ? kraw : qraw;
      const int kk = (k0 & 511) + lq * 8;
      bf16x8 v0 = *(const bf16x8*)(ap + tk0 * 512 + kk);
      bf16x8 v1 = *(const bf16x8*)(ap + tk1 * 512 + kk);
      const float s0 = dk ? ik0 : iq0, s1 = dk ? ik1 : iq1;
      bf16x8 o0, o1;
      if (dk) {
        f32x4 c0 = *(const f32x4*)&ctx_l[kk];
        f32x4 c1 = *(const f32x4*)&ctx_l[kk + 4];
        #pragma unroll
        for (int j = 0; j < 4; ++j) {
          o0[j]     = (__bf16)((float)v0[j]     * s0 * c0[j]);
          o0[4 + j] = (__bf16)((float)v0[4 + j] * s0 * c1[j]);
          o1[j]     = (__bf16)((float)v1[j]     * s1 * c0[j]);
          o1[4 + j] = (__bf16)((float)v1[4 + j] * s1 * c1[j]);
        }
      } else {
        #pragma unroll
        for (int j = 0; j < 8; ++j) {
          o0[j] = (__bf16)((float)v0[j] * s0);
          o1[j] = (__bf16)((float)v1[j] * s1);
        }
      }
      *(bf16x8*)(As + rA0 * 1024 + l * 16) = o0;
      *(bf16x8*)(As + rA1 * 1024 + l * 16) = o1;
    }
    __syncthreads();
    bf16x8 af[4];
    #pragma unroll
    for (int rb = 0; rb < 4; ++rb)
      af[rb] = *(const bf16x8*)(As + ((w & 1) * 4 + rb) * 1024 + l * 16);
    #pragma unroll
    for (int cb = 0; cb < 4; ++cb) {
      bf16x8 bf = *(const bf16x8*)(Bs + ((w >> 1) * 4 + cb) * 1024 + l * 16);
      #pragma unroll
      for (int rb = 0; rb < 4; ++rb)
        acc[rb][cb] = __builtin_amdgcn_mfma_f32_16x16x32_bf16(af[rb], bf, acc[rb][cb], 0, 0, 0);
    }
    __syncthreads();
  }

  const int colb = nt * 128 + (w >> 1) * 64;
  float bv[4];
  #pragma unroll
  for (int cb = 0; cb < 4; ++cb) bv[cb] = bpf[colb + cb * 16 + li];
  #pragma unroll
  for (int rb = 0; rb < 4; ++rb) {
    int nrow = m0 + (w & 1) * 64 + rb * 16 + lq * 4;
    if (nrow < 784) {
      #pragma unroll
      for (int cb = 0; cb < 4; ++cb) {
        f32x4 v;
        #pragma unroll
        for (int j = 0; j < 4; ++j) v[j] = acc[rb][cb][j] + bv[cb];
        *(f32x4*)&out[((size_t)b * 512 + colb + cb * 16 + li) * 784 + nrow] = v;
      }
    }
  }
}

extern "C" void kernel_launch(void* const* d_in, const int* in_sizes, int n_in,
                              void* d_out, int out_size, void* d_ws, size_t ws_size,
                              hipStream_t stream) {
  const float* x   = (const float*)d_in[0];
  const float* Wq  = (const float*)d_in[1];
  const float* bq  = (const float*)d_in[2];
  const float* Wk  = (const float*)d_in[3];
  const float* bk  = (const float*)d_in[4];
  const float* wg  = (const float*)d_in[5];
  const float* Wp  = (const float*)d_in[6];
  const float* bp  = (const float*)d_in[7];
  const float* Wf  = (const float*)d_in[8];
  const float* bfv = (const float*)d_in[9];
  float* out = (float*)d_out;
  char* ws = (char*)d_ws;

  const size_t SZRAW = (size_t)MTOT * 512 * 2;        // 51,380,224 B
  const size_t SZXT  = (size_t)32 * 784 * 512 * 2;    // 25,690,112 B (one 32-batch slice)
  size_t off = 0;
  __bf16* qraw = (__bf16*)(ws + off); off += SZRAW;
  __bf16* kraw = (__bf16*)(ws + off); off += SZRAW;
  __bf16* xT   = (__bf16*)(ws + off); off += SZXT;
  __bf16* WqT  = (__bf16*)(ws + off); off += 524288;
  __bf16* WkT  = (__bf16*)(ws + off); off += 524288;
  __bf16* WcT  = (__bf16*)(ws + off); off += 1048576;
  float*  bpf  = (float*) (ws + off); off += 2048;
  float*  psqQ = (float*) (ws + off); off += (size_t)8 * MTOT * 4;
  float*  psqK = (float*) (ws + off); off += (size_t)8 * MTOT * 4;
  float*  gdo  = (float*) (ws + off); off += (size_t)8 * MTOT * 4;
  float*  invqA = (float*)(ws + off); off += (size_t)MTOT * 4;
  float*  invkA = (float*)(ws + off); off += (size_t)MTOT * 4;
  float*  coefA = (float*)(ws + off); off += (size_t)MTOT * 4;
  float*  gA    = (float*)(ws + off); off += (size_t)MTOT * 4;
  float*  ctx   = (float*)(ws + off); off += 131072;
  // total ~136.3 MB

  k_prep_t<<<dim3(16, 16), dim3(32, 8), 0, stream>>>(Wq, Wk, WqT, WkT);
  k_prep_w<<<dim3(64),     dim3(512),   0, stream>>>(Wp, Wf, bp, bfv, WcT, bpf);
  for (int s = 0; s < 2; ++s) {
    k_xt  <<<dim3(25, 16, 32), dim3(32, 8), 0, stream>>>(x, xT, s * 32);
    k_gemm<<<dim3(896),        dim3(256),   0, stream>>>(xT, WqT, WkT, bq, bk, wg, s * 32,
                                                         qraw, kraw, psqQ, psqK, gdo);
  }
  k_normc<<<dim3(196),   dim3(256), 0, stream>>>(psqQ, psqK, gdo, invqA, invkA, coefA, gA);
  k_pctx <<<dim3(4, 64), dim3(512), 0, stream>>>(qraw, coefA, gA, ctx);
  k_out  <<<dim3(1792),  dim3(256), 0, stream>>>(qraw, kraw, invqA, invkA, ctx, WcT, bpf, out);
}

// Round 10
// 402.385 us; speedup vs baseline: 1.1134x; 1.0158x over previous
//
#include <hip/hip_runtime.h>

#define EPSN 1e-12f
#define SCALE_F 0.044194173824159216f  // 512^-0.5
#define MTOT 50176

typedef __bf16 bf16x8 __attribute__((ext_vector_type(8)));
typedef float  f32x4  __attribute__((ext_vector_type(4)));

__device__ __forceinline__ void gld16(const void* src, void* dst) {
  __builtin_amdgcn_global_load_lds(
      (const __attribute__((address_space(1))) unsigned int*)src,
      (__attribute__((address_space(3))) unsigned int*)dst, 16, 0, 0);
}

// ---------------- prep: xT[bl][n][c] = bf16(x[b0+bl][c][n]) ----------------
__global__ __launch_bounds__(256) void k_xt(const float* __restrict__ x,
                                            __bf16* __restrict__ xT, int b0) {
  __shared__ float T[32][33];
  const int n0 = blockIdx.x * 32, c0 = blockIdx.y * 32;
  const int bl = blockIdx.z, b = b0 + bl;
  const int dx = threadIdx.x, ty = threadIdx.y;   // 32, 8
  #pragma unroll
  for (int pp = 0; pp < 4; ++pp) {
    int c = ty + pp * 8;
    int n = n0 + dx;
    T[c][dx] = (n < 784) ? x[((size_t)b * 512 + c0 + c) * 784 + n] : 0.f;
  }
  __syncthreads();
  #pragma unroll
  for (int pp = 0; pp < 4; ++pp) {
    int n = ty + pp * 8;
    if (n0 + n < 784)
      xT[((size_t)bl * 784 + n0 + n) * 512 + c0 + dx] = (__bf16)T[dx][n];
  }
}

// ---------------- prep: WqT/WkT bf16 [d][c] = W[c][d], LDS tile transpose ----------------
__global__ __launch_bounds__(256) void k_prep_t(const float* __restrict__ Wq,
                                                const float* __restrict__ Wk,
                                                __bf16* __restrict__ WqT,
                                                __bf16* __restrict__ WkT) {
  __shared__ float Tq[32][33], Tk[32][33];
  const int c0 = blockIdx.x * 32, d0 = blockIdx.y * 32;
  const int dx = threadIdx.x, cy = threadIdx.y;  // 32, 8
  #pragma unroll
  for (int p = 0; p < 4; ++p) {
    int c = cy + p * 8;
    Tq[c][dx] = Wq[(size_t)(c0 + c) * 512 + d0 + dx];
    Tk[c][dx] = Wk[(size_t)(c0 + c) * 512 + d0 + dx];
  }
  __syncthreads();
  #pragma unroll
  for (int p = 0; p < 4; ++p) {
    int d = cy + p * 8;
    WqT[(size_t)(d0 + d) * 512 + c0 + dx] = (__bf16)Tq[dx][d];
    WkT[(size_t)(d0 + d) * 512 + c0 + dx] = (__bf16)Tk[dx][d];
  }
}

// ---- prep: WcT[d][kk]: kk<512 -> (Wp@Wf)[kk][d]; kk>=512 -> Wf[kk-512][d]. bpf[d]=bp@Wf+bf
__global__ __launch_bounds__(512) void k_prep_w(const float* __restrict__ Wp,
                                                const float* __restrict__ Wf,
                                                const float* __restrict__ bp,
                                                const float* __restrict__ bfv,
                                                __bf16* __restrict__ WcT,
                                                float* __restrict__ bpf) {
  const int kk0 = blockIdx.x * 2;
  const int d = threadIdx.x;
  float acc0 = 0.f, acc1 = 0.f, bacc = 0.f;
  const bool dobp = (blockIdx.x == 0);
  for (int c = 0; c < 512; ++c) {
    float wf = Wf[(size_t)c * 512 + d];
    acc0 = fmaf(Wp[(size_t)kk0 * 512 + c],       wf, acc0);
    acc1 = fmaf(Wp[(size_t)(kk0 + 1) * 512 + c], wf, acc1);
    if (dobp) bacc = fmaf(bp[c], wf, bacc);
  }
  WcT[(size_t)d * 1024 + kk0]           = (__bf16)acc0;
  WcT[(size_t)d * 1024 + kk0 + 1]       = (__bf16)acc1;
  WcT[(size_t)d * 1024 + 512 + kk0]     = (__bf16)Wf[(size_t)kk0 * 512 + d];
  WcT[(size_t)d * 1024 + 512 + kk0 + 1] = (__bf16)Wf[(size_t)(kk0 + 1) * 512 + d];
  if (dobp) bpf[d] = bacc + bfv[d];
}

// ---------------- merged Q+K GEMM: 128 tok x 128 d, all-gld16, dbuf + issue-early ----------------
__global__ __launch_bounds__(256, 2) void k_gemm(const __bf16* __restrict__ xT,
                                                 const __bf16* __restrict__ WqT,
                                                 const __bf16* __restrict__ WkT,
                                                 const float* __restrict__ bq,
                                                 const float* __restrict__ bk,
                                                 const float* __restrict__ wg,
                                                 const int b0,
                                                 __bf16* __restrict__ qraw,
                                                 __bf16* __restrict__ kraw,
                                                 float* __restrict__ psqQ,
                                                 float* __restrict__ psqK,
                                                 float* __restrict__ gdo) {
  __shared__ __align__(1024) unsigned char stg[2][24576];   // As 8K | BQs 8K | BKs 8K
  const int t = threadIdx.x, l = t & 63, w = t >> 6;
  const int li = l & 15, lq = l >> 4;
  const int p = blockIdx.x;
  const int xq = p & 7, q2 = p >> 3;
  const int nt = q2 & 3;
  const int g = (q2 >> 2) * 8 + xq;       // 0..223
  const int bl = g / 7, mt = g % 7;
  const int b = b0 + bl;
  const int m0 = mt * 128;

  const int r0 = 2 * w, r1 = r0 + 1;
  int row0 = m0 + r0 * 16 + li; if (row0 > 783) row0 = 783;
  int row1 = m0 + r1 * 16 + li; if (row1 > 783) row1 = 783;
  const __bf16* a0s = xT + ((size_t)bl * 784 + row0) * 512 + lq * 8;
  const __bf16* a1s = xT + ((size_t)bl * 784 + row1) * 512 + lq * 8;
  const __bf16* q0s = WqT + (size_t)(nt * 128 + r0 * 16 + li) * 512 + lq * 8;
  const __bf16* q1s = WqT + (size_t)(nt * 128 + r1 * 16 + li) * 512 + lq * 8;
  const __bf16* k0s = WkT + (size_t)(nt * 128 + r0 * 16 + li) * 512 + lq * 8;
  const __bf16* k1s = WkT + (size_t)(nt * 128 + r1 * 16 + li) * 512 + lq * 8;

  f32x4 accQ[4][4] = {}, accK[4][4] = {};

  auto stage = [&](int buf, int ks) {
    const int kk = (ks > 15 ? 15 : ks) * 32;
    gld16(a0s + kk, stg[buf] + r0 * 1024);
    gld16(a1s + kk, stg[buf] + r1 * 1024);
    gld16(q0s + kk, stg[buf] + 8192 + r0 * 1024);
    gld16(q1s + kk, stg[buf] + 8192 + r1 * 1024);
    gld16(k0s + kk, stg[buf] + 16384 + r0 * 1024);
    gld16(k1s + kk, stg[buf] + 16384 + r1 * 1024);
  };
  auto mstep = [&](int buf) {
    bf16x8 af[4];
    #pragma unroll
    for (int rb = 0; rb < 4; ++rb)
      af[rb] = *(const bf16x8*)(stg[buf] + ((w & 1) * 4 + rb) * 1024 + l * 16);
    #pragma unroll
    for (int cb = 0; cb < 4; ++cb) {
      bf16x8 bq8 = *(const bf16x8*)(stg[buf] + 8192 + ((w >> 1) * 4 + cb) * 1024 + l * 16);
      #pragma unroll
      for (int rb = 0; rb < 4; ++rb)
        accQ[rb][cb] = __builtin_amdgcn_mfma_f32_16x16x32_bf16(af[rb], bq8, accQ[rb][cb], 0, 0, 0);
      bf16x8 bk8 = *(const bf16x8*)(stg[buf] + 16384 + ((w >> 1) * 4 + cb) * 1024 + l * 16);
      #pragma unroll
      for (int rb = 0; rb < 4; ++rb)
        accK[rb][cb] = __builtin_amdgcn_mfma_f32_16x16x32_bf16(af[rb], bk8, accK[rb][cb], 0, 0, 0);
    }
  };

  stage(0, 0);
  asm volatile("s_waitcnt vmcnt(0)" ::: "memory");
  __builtin_amdgcn_s_barrier();
  __builtin_amdgcn_sched_barrier(0);
  #pragma unroll 1
  for (int ks = 0; ks < 16; ++ks) {
    stage((ks + 1) & 1, ks + 1);            // issue next tile FIRST (clamped at tail)
    __builtin_amdgcn_sched_barrier(0);
    mstep(ks & 1);                          // compute current while loads fly
    asm volatile("s_waitcnt vmcnt(0)" ::: "memory");
    __builtin_amdgcn_s_barrier();
    __builtin_amdgcn_sched_barrier(0);
  }

  // epilogue: bias, raw stores, per-colgroup partial sumsq (Q,K) + gdot (Q)
  const int colb = nt * 128 + (w >> 1) * 64;
  const int cg = nt * 2 + (w >> 1);
  float bqv[4], bkv[4], wv[4];
  #pragma unroll
  for (int cb = 0; cb < 4; ++cb) {
    int col = colb + cb * 16 + li;
    bqv[cb] = bq[col]; bkv[cb] = bk[col]; wv[cb] = wg[col];
  }
  #pragma unroll
  for (int rb = 0; rb < 4; ++rb)
    #pragma unroll
    for (int j = 0; j < 4; ++j) {
      int rowg = m0 + (w & 1) * 64 + rb * 16 + lq * 4 + j;
      bool ok = rowg < 784;
      size_t token = (size_t)b * 784 + rowg;
      float ssq = 0.f, ssk = 0.f, sg = 0.f;
      #pragma unroll
      for (int cb = 0; cb < 4; ++cb) {
        float vq = accQ[rb][cb][j] + bqv[cb];
        float vk = accK[rb][cb][j] + bkv[cb];
        ssq = fmaf(vq, vq, ssq);
        ssk = fmaf(vk, vk, ssk);
        sg  = fmaf(vq, wv[cb], sg);
        if (ok) {
          qraw[token * 512 + colb + cb * 16 + li] = (__bf16)vq;
          kraw[token * 512 + colb + cb * 16 + li] = (__bf16)vk;
        }
      }
      ssq += __shfl_xor(ssq, 1); ssq += __shfl_xor(ssq, 2); ssq += __shfl_xor(ssq, 4); ssq += __shfl_xor(ssq, 8);
      ssk += __shfl_xor(ssk, 1); ssk += __shfl_xor(ssk, 2); ssk += __shfl_xor(ssk, 4); ssk += __shfl_xor(ssk, 8);
      sg  += __shfl_xor(sg, 1);  sg  += __shfl_xor(sg, 2);  sg  += __shfl_xor(sg, 4);  sg  += __shfl_xor(sg, 8);
      if (ok && li == 0) {
        psqQ[(size_t)cg * MTOT + token] = ssq;
        psqK[(size_t)cg * MTOT + token] = ssk;
        gdo [(size_t)cg * MTOT + token] = sg;
      }
    }
}

// ---------------- per-token combine: invq, invk, coef, g ----------------
__global__ __launch_bounds__(256) void k_normc(const float* __restrict__ psqQ,
                                               const float* __restrict__ psqK,
                                               const float* __restrict__ gdo,
                                               float* __restrict__ invqA,
                                               float* __restrict__ invkA,
                                               float* __restrict__ coefA,
                                               float* __restrict__ gA) {
  const int tkn = blockIdx.x * 256 + threadIdx.x;
  if (tkn >= MTOT) return;
  float sq = 0.f, sk = 0.f, gd = 0.f;
  #pragma unroll
  for (int cg = 0; cg < 8; ++cg) {
    sq += psqQ[(size_t)cg * MTOT + tkn];
    sk += psqK[(size_t)cg * MTOT + tkn];
    gd += gdo[(size_t)cg * MTOT + tkn];
  }
  float invq = 1.f / fmaxf(sqrtf(sq), EPSN);
  float invk = 1.f / fmaxf(sqrtf(sk), EPSN);
  float gv = gd * invq;
  invqA[tkn] = invq;
  invkA[tkn] = invk;
  coefA[tkn] = gv * invq;
  gA[tkn]    = gv;
}

// ---------------- per-batch: ||g|| + ctx[d] = alpha * sum_n coef[n]*qraw[n,d] ----------------
__global__ __launch_bounds__(512) void k_pctx(const __bf16* __restrict__ qraw,
                                              const float* __restrict__ coefA,
                                              const float* __restrict__ gA,
                                              float* __restrict__ ctx) {
  __shared__ float wred[8];
  __shared__ float part[4][128];
  const int ch = blockIdx.x, b = blockIdx.y, t = threadIdx.x;
  const size_t base = (size_t)b * 784;
  float gsq;
  { float gv = gA[base + t]; gsq = gv * gv; }
  if (t + 512 < 784) { float gv = gA[base + t + 512]; gsq = fmaf(gv, gv, gsq); }
  gsq += __shfl_xor(gsq, 1);  gsq += __shfl_xor(gsq, 2);  gsq += __shfl_xor(gsq, 4);
  gsq += __shfl_xor(gsq, 8);  gsq += __shfl_xor(gsq, 16); gsq += __shfl_xor(gsq, 32);
  if ((t & 63) == 0) wred[t >> 6] = gsq;
  __syncthreads();
  float tot = 0.f;
  #pragma unroll
  for (int i = 0; i < 8; ++i) tot += wred[i];
  const float alpha = SCALE_F / fmaxf(sqrtf(tot) * SCALE_F, EPSN);
  const int dof = t & 127, s = t >> 7;
  const int nb = s * 196;
  const __bf16* qb = qraw + (base + nb) * 512 + ch * 128 + dof;
  const float* cf = coefA + base + nb;
  float a0 = 0.f, a1 = 0.f, a2 = 0.f, a3 = 0.f;
  for (int n = 0; n < 196; n += 4) {
    a0 = fmaf(cf[n],     (float)qb[(size_t)n * 512],       a0);
    a1 = fmaf(cf[n + 1], (float)qb[(size_t)(n + 1) * 512], a1);
    a2 = fmaf(cf[n + 2], (float)qb[(size_t)(n + 2) * 512], a2);
    a3 = fmaf(cf[n + 3], (float)qb[(size_t)(n + 3) * 512], a3);
  }
  part[s][dof] = (a0 + a1) + (a2 + a3);
  __syncthreads();
  if (t < 128) {
    float sum = part[0][t] + part[1][t] + part[2][t] + part[3][t];
    ctx[(size_t)b * 512 + ch * 128 + t] = alpha * sum;
  }
}

// ---------------- final GEMM: out = ([ctx.(kraw.invk) | qraw.invq] @ WcT^T + bpf)^T ----------------
// dbuf + issue-early: B gld16, A reg-loaded at step start, scaled+ds_written after vmcnt.
__global__ __launch_bounds__(256, 3) void k_out(const __bf16* __restrict__ qraw,
                                                const __bf16* __restrict__ kraw,
                                                const float* __restrict__ invqA,
                                                const float* __restrict__ invkA,
                                                const float* __restrict__ ctx,
                                                const __bf16* __restrict__ WcT,
                                                const float* __restrict__ bpf,
                                                float* __restrict__ out) {
  __shared__ __align__(1024) unsigned char stg[2][16384];   // As 8K | Bs 8K per buf
  __shared__ float ctx_l[512];
  const int t = threadIdx.x, l = t & 63, w = t >> 6;
  const int li = l & 15, lq = l >> 4;
  const int p = blockIdx.x;
  const int xq = p & 7, q2 = p >> 3;
  const int nt = q2 & 3;
  const int g = (q2 >> 2) * 8 + xq;       // 0..447
  const int b = g / 7, mt = g % 7;
  const int m0 = mt * 128;

  ctx_l[t]       = ctx[(size_t)b * 512 + t];
  ctx_l[t + 256] = ctx[(size_t)b * 512 + t + 256];
  __syncthreads();

  const int rA0 = w, rA1 = w + 4;
  int row0 = m0 + rA0 * 16 + li; if (row0 > 783) row0 = 783;
  int row1 = m0 + rA1 * 16 + li; if (row1 > 783) row1 = 783;
  const size_t tk0 = (size_t)b * 784 + row0, tk1 = (size_t)b * 784 + row1;
  const float iq0 = invqA[tk0], ik0 = invkA[tk0];
  const float iq1 = invqA[tk1], ik1 = invkA[tk1];
  const __bf16* wpB0 = WcT + (size_t)(nt * 128 + (2 * w) * 16 + li) * 1024 + lq * 8;
  const __bf16* wpB1 = WcT + (size_t)(nt * 128 + (2 * w + 1) * 16 + li) * 1024 + lq * 8;

  f32x4 acc[4][4] = {};

  auto stageB = [&](int buf, int ks) {
    const int kk = (ks > 31 ? 31 : ks) * 32;
    gld16(wpB0 + kk, stg[buf] + 8192 + (2 * w) * 1024);
    gld16(wpB1 + kk, stg[buf] + 8192 + (2 * w + 1) * 1024);
  };
  auto loadA = [&](bf16x8& v0, bf16x8& v1, int ks) {
    const int kk = ks > 31 ? 31 : ks;
    const __bf16* ap = (kk < 16) ? kraw : qraw;
    const int off = (kk & 15) * 32 + lq * 8;
    v0 = *(const bf16x8*)(ap + tk0 * 512 + off);
    v1 = *(const bf16x8*)(ap + tk1 * 512 + off);
  };
  auto writeA = [&](int buf, bf16x8 v0, bf16x8 v1, int ks) {
    const int kk = ks > 31 ? 31 : ks;
    bf16x8 o0, o1;
    if (kk < 16) {
      const int kl = (kk & 15) * 32 + lq * 8;
      f32x4 c0 = *(const f32x4*)&ctx_l[kl];
      f32x4 c1 = *(const f32x4*)&ctx_l[kl + 4];
      #pragma unroll
      for (int j = 0; j < 4; ++j) {
        o0[j]     = (__bf16)((float)v0[j]     * ik0 * c0[j]);
        o0[4 + j] = (__bf16)((float)v0[4 + j] * ik0 * c1[j]);
        o1[j]     = (__bf16)((float)v1[j]     * ik1 * c0[j]);
        o1[4 + j] = (__bf16)((float)v1[4 + j] * ik1 * c1[j]);
      }
    } else {
      #pragma unroll
      for (int j = 0; j < 8; ++j) {
        o0[j] = (__bf16)((float)v0[j] * iq0);
        o1[j] = (__bf16)((float)v1[j] * iq1);
      }
    }
    *(bf16x8*)(stg[buf] + rA0 * 1024 + l * 16) = o0;
    *(bf16x8*)(stg[buf] + rA1 * 1024 + l * 16) = o1;
  };
  auto mstep = [&](int buf) {
    bf16x8 af[4];
    #pragma unroll
    for (int rb = 0; rb < 4; ++rb)
      af[rb] = *(const bf16x8*)(stg[buf] + ((w & 1) * 4 + rb) * 1024 + l * 16);
    #pragma unroll
    for (int cb = 0; cb < 4; ++cb) {
      bf16x8 bf = *(const bf16x8*)(stg[buf] + 8192 + ((w >> 1) * 4 + cb) * 1024 + l * 16);
      #pragma unroll
      for (int rb = 0; rb < 4; ++rb)
        acc[rb][cb] = __builtin_amdgcn_mfma_f32_16x16x32_bf16(af[rb], bf, acc[rb][cb], 0, 0, 0);
    }
  };

  // prologue: stage tile 0 into buf0
  {
    bf16x8 vA0, vA1;
    loadA(vA0, vA1, 0);
    stageB(0, 0);
    asm volatile("s_waitcnt vmcnt(0)" ::: "memory");
    writeA(0, vA0, vA1, 0);
    asm volatile("s_waitcnt lgkmcnt(0)" ::: "memory");
    __builtin_amdgcn_s_barrier();
    __builtin_amdgcn_sched_barrier(0);
  }
  #pragma unroll 1
  for (int ks = 0; ks < 32; ++ks) {
    bf16x8 nA0, nA1;
    loadA(nA0, nA1, ks + 1);                // issue next-tile loads FIRST (clamped tail)
    stageB((ks + 1) & 1, ks + 1);
    __builtin_amdgcn_sched_barrier(0);
    mstep(ks & 1);                          // compute current while loads fly
    asm volatile("s_waitcnt vmcnt(0)" ::: "memory");
    writeA((ks + 1) & 1, nA0, nA1, ks + 1); // A regs landed; write to other buffer
    asm volatile("s_waitcnt lgkmcnt(0)" ::: "memory");
    __builtin_amdgcn_s_barrier();
    __builtin_amdgcn_sched_barrier(0);
  }

  const int colb = nt * 128 + (w >> 1) * 64;
  float bv[4];
  #pragma unroll
  for (int cb = 0; cb < 4; ++cb) bv[cb] = bpf[colb + cb * 16 + li];
  #pragma unroll
  for (int rb = 0; rb < 4; ++rb) {
    int nrow = m0 + (w & 1) * 64 + rb * 16 + lq * 4;
    if (nrow < 784) {
      #pragma unroll
      for (int cb = 0; cb < 4; ++cb) {
        f32x4 v;
        #pragma unroll
        for (int j = 0; j < 4; ++j) v[j] = acc[rb][cb][j] + bv[cb];
        *(f32x4*)&out[((size_t)b * 512 + colb + cb * 16 + li) * 784 + nrow] = v;
      }
    }
  }
}

extern "C" void kernel_launch(void* const* d_in, const int* in_sizes, int n_in,
                              void* d_out, int out_size, void* d_ws, size_t ws_size,
                              hipStream_t stream) {
  const float* x   = (const float*)d_in[0];
  const float* Wq  = (const float*)d_in[1];
  const float* bq  = (const float*)d_in[2];
  const float* Wk  = (const float*)d_in[3];
  const float* bk  = (const float*)d_in[4];
  const float* wg  = (const float*)d_in[5];
  const float* Wp  = (const float*)d_in[6];
  const float* bp  = (const float*)d_in[7];
  const float* Wf  = (const float*)d_in[8];
  const float* bfv = (const float*)d_in[9];
  float* out = (float*)d_out;
  char* ws = (char*)d_ws;

  const size_t SZRAW = (size_t)MTOT * 512 * 2;        // 51,380,224 B
  const size_t SZXT  = (size_t)32 * 784 * 512 * 2;    // 25,690,112 B (one 32-batch slice)
  size_t off = 0;
  __bf16* qraw = (__bf16*)(ws + off); off += SZRAW;
  __bf16* kraw = (__bf16*)(ws + off); off += SZRAW;
  __bf16* xT   = (__bf16*)(ws + off); off += SZXT;
  __bf16* WqT  = (__bf16*)(ws + off); off += 524288;
  __bf16* WkT  = (__bf16*)(ws + off); off += 524288;
  __bf16* WcT  = (__bf16*)(ws + off); off += 1048576;
  float*  bpf  = (float*) (ws + off); off += 2048;
  float*  psqQ = (float*) (ws + off); off += (size_t)8 * MTOT * 4;
  float*  psqK = (float*) (ws + off); off += (size_t)8 * MTOT * 4;
  float*  gdo  = (float*) (ws + off); off += (size_t)8 * MTOT * 4;
  float*  invqA = (float*)(ws + off); off += (size_t)MTOT * 4;
  float*  invkA = (float*)(ws + off); off += (size_t)MTOT * 4;
  float*  coefA = (float*)(ws + off); off += (size_t)MTOT * 4;
  float*  gA    = (float*)(ws + off); off += (size_t)MTOT * 4;
  float*  ctx   = (float*)(ws + off); off += 131072;
  // total ~136.3 MB

  k_prep_t<<<dim3(16, 16), dim3(32, 8), 0, stream>>>(Wq, Wk, WqT, WkT);
  k_prep_w<<<dim3(256),    dim3(512),   0, stream>>>(Wp, Wf, bp, bfv, WcT, bpf);
  for (int s = 0; s < 2; ++s) {
    k_xt  <<<dim3(25, 16, 32), dim3(32, 8), 0, stream>>>(x, xT, s * 32);
    k_gemm<<<dim3(896),        dim3(256),   0, stream>>>(xT, WqT, WkT, bq, bk, wg, s * 32,
                                                         qraw, kraw, psqQ, psqK, gdo);
  }
  k_normc<<<dim3(196),   dim3(256), 0, stream>>>(psqQ, psqK, gdo, invqA, invkA, coefA, gA);
  k_pctx <<<dim3(4, 64), dim3(512), 0, stream>>>(qraw, coefA, gA, ctx);
  k_out  <<<dim3(1792),  dim3(256), 0, stream>>>(qraw, kraw, invqA, invkA, ctx, WcT, bpf, out);
}